// Round 1
// baseline (392.690 us; speedup 1.0000x reference)
//
#include <hip/hip_runtime.h>

#define NFR   4
#define NLOCC 2048
#define NNEIN 64
#define EMB   128
#define PDIM  64
#define NH    8
#define HDIM  16
#define LNEPS 1e-5f
#define NROW  (NFR*NLOCC)   // 8192

__device__ __forceinline__ void fma4(float4& acc, const float4 a, const float4 b) {
    acc.x = fmaf(a.x, b.x, acc.x);
    acc.y = fmaf(a.y, b.y, acc.y);
    acc.z = fmaf(a.z, b.z, acc.z);
    acc.w = fmaf(a.w, b.w, acc.w);
}
__device__ __forceinline__ float hsum4(const float4 a) {
    return (a.x + a.y) + (a.z + a.w);
}

// ---------------- Kernel 1: LN(query) + q,k,v projections ----------------
// grid 512 blocks x 256 threads, 16 rows per block
__global__ __launch_bounds__(256) void qkv_kernel(
    const float* __restrict__ query,
    const float* __restrict__ ln_g, const float* __restrict__ ln_b,
    const float* __restrict__ Wq, const float* __restrict__ Wk, const float* __restrict__ Wv,
    float* __restrict__ q_ws, float* __restrict__ k_ws, float* __restrict__ v_ws)
{
    __shared__ float gb_s[2][EMB];
    __shared__ float qn_s[16][EMB];
    const int t = threadIdx.x;
    const int rowbase = blockIdx.x * 16;

    // stage ln gamma/beta
    if (t < 64) {
        const float* src = (t < 32) ? ln_g : ln_b;
        ((float4*)gb_s[t >> 5])[t & 31] = ((const float4*)src)[t & 31];
    }

    // each thread: 8 floats of one query row (16 threads per row)
    const int r   = t >> 4;   // 0..15
    const int seg = t & 15;   // 0..15
    float4 x0 = ((const float4*)query)[(size_t)(rowbase + r) * 32 + seg * 2 + 0];
    float4 x1 = ((const float4*)query)[(size_t)(rowbase + r) * 32 + seg * 2 + 1];
    float s  = (x0.x + x0.y + x0.z + x0.w) + (x1.x + x1.y + x1.z + x1.w);
    float ss = x0.x*x0.x + x0.y*x0.y + x0.z*x0.z + x0.w*x0.w
             + x1.x*x1.x + x1.y*x1.y + x1.z*x1.z + x1.w*x1.w;
    #pragma unroll
    for (int m = 1; m < 16; m <<= 1) {
        s  += __shfl_xor(s,  m, 64);
        ss += __shfl_xor(ss, m, 64);
    }
    const float mean = s * (1.0f / 128.0f);
    const float var  = ss * (1.0f / 128.0f) - mean * mean;
    const float rstd = rsqrtf(var + LNEPS);
    __syncthreads();   // gb_s ready

    const int c0 = seg * 8;
    float4 o0, o1;
    o0.x = (x0.x - mean) * rstd * gb_s[0][c0+0] + gb_s[1][c0+0];
    o0.y = (x0.y - mean) * rstd * gb_s[0][c0+1] + gb_s[1][c0+1];
    o0.z = (x0.z - mean) * rstd * gb_s[0][c0+2] + gb_s[1][c0+2];
    o0.w = (x0.w - mean) * rstd * gb_s[0][c0+3] + gb_s[1][c0+3];
    o1.x = (x1.x - mean) * rstd * gb_s[0][c0+4] + gb_s[1][c0+4];
    o1.y = (x1.y - mean) * rstd * gb_s[0][c0+5] + gb_s[1][c0+5];
    o1.z = (x1.z - mean) * rstd * gb_s[0][c0+6] + gb_s[1][c0+6];
    o1.w = (x1.w - mean) * rstd * gb_s[0][c0+7] + gb_s[1][c0+7];
    ((float4*)qn_s[r])[seg*2 + 0] = o0;
    ((float4*)qn_s[r])[seg*2 + 1] = o1;
    __syncthreads();

    // matvec: thread owns 4 consecutive cols x 2 rows
    const int dblk = t & 31;       // col block: d0 = dblk*4
    const int r0   = (t >> 5) * 2; // rows r0, r0+1
    const float* Ws[3] = {Wq, Wk, Wv};
    float*       Os[3] = {q_ws, k_ws, v_ws};
    const float4* qn0 = (const float4*)qn_s[r0];
    const float4* qn1 = (const float4*)qn_s[r0 + 1];

    for (int w = 0; w < 3; ++w) {
        const float4* W4 = (const float4*)Ws[w];
        float4 acc0[4], acc1[4];
        #pragma unroll
        for (int i = 0; i < 4; ++i) {
            acc0[i] = make_float4(0.f, 0.f, 0.f, 0.f);
            acc1[i] = make_float4(0.f, 0.f, 0.f, 0.f);
        }
        #pragma unroll 8
        for (int e4 = 0; e4 < 32; ++e4) {
            float4 a0 = qn0[e4];
            float4 a1 = qn1[e4];
            #pragma unroll
            for (int i = 0; i < 4; ++i) {
                float4 wv = W4[(size_t)(dblk * 4 + i) * 32 + e4];
                fma4(acc0[i], a0, wv);
                fma4(acc1[i], a1, wv);
            }
        }
        const float scale = (w == 0) ? 0.25f : 1.0f;  // HD^-0.5 folded into q
        float4 res0, res1;
        res0.x = hsum4(acc0[0]) * scale; res0.y = hsum4(acc0[1]) * scale;
        res0.z = hsum4(acc0[2]) * scale; res0.w = hsum4(acc0[3]) * scale;
        res1.x = hsum4(acc1[0]) * scale; res1.y = hsum4(acc1[1]) * scale;
        res1.z = hsum4(acc1[2]) * scale; res1.w = hsum4(acc1[3]) * scale;
        ((float4*)Os[w])[(size_t)(rowbase + r0) * 32 + dblk]     = res0;
        ((float4*)Os[w])[(size_t)(rowbase + r0 + 1) * 32 + dblk] = res1;
    }
}

// ---------------- Kernel 2: pair LN + bias + attn + softmax + force ----------------
// grid 8192 blocks (one per (f,l)) x 256 threads (4 threads per neighbor)
__global__ __launch_bounds__(256) void attn_force_kernel(
    const float* __restrict__ pair, const int* __restrict__ nlist,
    const float* __restrict__ delta_pos, const float* __restrict__ attn_mask,
    const float* __restrict__ pn_g, const float* __restrict__ pn_b,
    const float* __restrict__ Wbias, const float* __restrict__ bbias,
    const float* __restrict__ Wforce,
    const float* __restrict__ q_ws, const float* __restrict__ k_ws,
    const float* __restrict__ v_ws,
    float* __restrict__ out)
{
    __shared__ float q_s[EMB];
    __shared__ float wf_s[EMB];
    __shared__ float png_s[PDIM];
    __shared__ float pnb_s[PDIM];
    __shared__ float bb_s[NH];
    __shared__ float wbT[PDIM][NH];     // Wbias transposed: wbT[p][h]
    __shared__ float logit_s[NH][NNEIN];
    __shared__ float s_s[NNEIN];
    __shared__ int   nl_s[NNEIN];

    const int t   = threadIdx.x;
    const int bid = blockIdx.x;          // row = f*NLOC + l
    const int fr  = bid >> 11;
    const int l   = bid & 2047;

    // ---- staging ----
    if (t < 32)        ((float4*)q_s)[t]        = ((const float4*)(q_ws + (size_t)bid * EMB))[t];
    else if (t < 64)   ((float4*)wf_s)[t - 32]  = ((const float4*)Wforce)[t - 32];
    else if (t < 80)   ((int4*)nl_s)[t - 64]    = ((const int4*)(nlist + (size_t)bid * NNEIN))[t - 64];
    else if (t < 96)   ((float4*)png_s)[t - 80] = ((const float4*)pn_g)[t - 80];
    else if (t < 112)  ((float4*)pnb_s)[t - 96] = ((const float4*)pn_b)[t - 96];
    else if (t < 114)  ((float4*)bb_s)[t - 112] = ((const float4*)bbias)[t - 112];
    if (t >= 128) {
        int idx = t - 128;               // 0..127 ; Wbias is 8x64 = 128 float4
        float4 w4 = ((const float4*)Wbias)[idx];
        int h = idx >> 4, p0 = (idx & 15) * 4;
        wbT[p0 + 0][h] = w4.x; wbT[p0 + 1][h] = w4.y;
        wbT[p0 + 2][h] = w4.z; wbT[p0 + 3][h] = w4.w;
    }
    __syncthreads();

    const int n   = t >> 2;     // neighbor 0..63
    const int sub = t & 3;      // 0..3
    const int h0  = sub * 2, h1 = h0 + 1;

    // ---- pair LayerNorm (in registers) + bias dot ----
    const float4* prow = (const float4*)(pair + ((size_t)bid * NNEIN + n) * PDIM);
    float4 pr[4];
    #pragma unroll
    for (int i = 0; i < 4; ++i) pr[i] = prow[sub * 4 + i];
    float s = 0.f, ss = 0.f;
    #pragma unroll
    for (int i = 0; i < 4; ++i) {
        s  += (pr[i].x + pr[i].y) + (pr[i].z + pr[i].w);
        ss += pr[i].x*pr[i].x + pr[i].y*pr[i].y + pr[i].z*pr[i].z + pr[i].w*pr[i].w;
    }
    s  += __shfl_xor(s, 1, 64);  s  += __shfl_xor(s, 2, 64);
    ss += __shfl_xor(ss, 1, 64); ss += __shfl_xor(ss, 2, 64);
    const float mean = s * (1.0f / 64.0f);
    const float var  = ss * (1.0f / 64.0f) - mean * mean;
    const float rstd = rsqrtf(var + LNEPS);

    float bp[NH];
    #pragma unroll
    for (int h = 0; h < NH; ++h) bp[h] = 0.f;
    #pragma unroll
    for (int i = 0; i < 4; ++i) {
        const float pv[4] = {pr[i].x, pr[i].y, pr[i].z, pr[i].w};
        #pragma unroll
        for (int k = 0; k < 4; ++k) {
            const int col = sub * 16 + i * 4 + k;
            const float pn = (pv[k] - mean) * rstd * png_s[col] + pnb_s[col];
            const float4 wa = ((const float4*)wbT[col])[0];
            const float4 wb = ((const float4*)wbT[col])[1];
            bp[0] = fmaf(pn, wa.x, bp[0]); bp[1] = fmaf(pn, wa.y, bp[1]);
            bp[2] = fmaf(pn, wa.z, bp[2]); bp[3] = fmaf(pn, wa.w, bp[3]);
            bp[4] = fmaf(pn, wb.x, bp[4]); bp[5] = fmaf(pn, wb.y, bp[5]);
            bp[6] = fmaf(pn, wb.z, bp[6]); bp[7] = fmaf(pn, wb.w, bp[7]);
        }
    }
    #pragma unroll
    for (int m = 1; m < 4; m <<= 1)
        #pragma unroll
        for (int h = 0; h < NH; ++h) bp[h] += __shfl_xor(bp[h], m, 64);

    // ---- attn logits: dot16(q, gathered k) for this thread's 2 heads ----
    const int j = nl_s[n];
    const float4* krow = (const float4*)(k_ws + ((size_t)fr * NLOCC + j) * EMB);
    #pragma unroll
    for (int hi = 0; hi < 2; ++hi) {
        const int h = h0 + hi;
        float4 acc = make_float4(0.f, 0.f, 0.f, 0.f);
        #pragma unroll
        for (int j4 = 0; j4 < 4; ++j4)
            fma4(acc, krow[h * 4 + j4], ((const float4*)q_s)[h * 4 + j4]);
        const float mask = attn_mask[(((size_t)fr * NH + h) * NLOCC + l) * NNEIN + n];
        logit_s[h][n] = hsum4(acc) + bp[h] + bb_s[h] + mask;
    }
    __syncthreads();

    // ---- softmax over n (64) per head: one 32-lane half-wave per head ----
    {
        const int h = t >> 5, i = t & 31;
        float a = logit_s[h][i], b = logit_s[h][i + 32];
        float m = fmaxf(a, b);
        #pragma unroll
        for (int mm = 16; mm >= 1; mm >>= 1) m = fmaxf(m, __shfl_xor(m, mm, 64));
        float ea = __expf(a - m), eb = __expf(b - m);
        float sum = ea + eb;
        #pragma unroll
        for (int mm = 16; mm >= 1; mm >>= 1) sum += __shfl_xor(sum, mm, 64);
        const float inv = 1.0f / sum;
        logit_s[h][i]      = ea * inv;
        logit_s[h][i + 32] = eb * inv;
    }
    __syncthreads();

    // ---- s[n] = sum_h probs[h][n] * dot16(Wforce_h, v_gathered[n]_h) ----
    const float4* vrow = (const float4*)(v_ws + ((size_t)fr * NLOCC + j) * EMB);
    float sn = 0.f;
    #pragma unroll
    for (int hi = 0; hi < 2; ++hi) {
        const int h = h0 + hi;
        float4 acc = make_float4(0.f, 0.f, 0.f, 0.f);
        #pragma unroll
        for (int j4 = 0; j4 < 4; ++j4)
            fma4(acc, vrow[h * 4 + j4], ((const float4*)wf_s)[h * 4 + j4]);
        sn = fmaf(logit_s[h][n], hsum4(acc), sn);
    }
    sn += __shfl_xor(sn, 1, 64);
    sn += __shfl_xor(sn, 2, 64);
    if (sub == 0) s_s[n] = sn;
    __syncthreads();

    // ---- force[c] = sum_n s[n] * delta_pos[n][c] ----
    if (t < 64) {
        const float sv = s_s[t];
        const float* dp = delta_pos + ((size_t)bid * NNEIN + t) * 3;
        float f0 = sv * dp[0], f1 = sv * dp[1], f2 = sv * dp[2];
        #pragma unroll
        for (int mm = 32; mm >= 1; mm >>= 1) {
            f0 += __shfl_xor(f0, mm, 64);
            f1 += __shfl_xor(f1, mm, 64);
            f2 += __shfl_xor(f2, mm, 64);
        }
        if (t == 0) {
            out[(size_t)bid * 3 + 0] = f0;
            out[(size_t)bid * 3 + 1] = f1;
            out[(size_t)bid * 3 + 2] = f2;
        }
    }
}

extern "C" void kernel_launch(void* const* d_in, const int* in_sizes, int n_in,
                              void* d_out, int out_size, void* d_ws, size_t ws_size,
                              hipStream_t stream) {
    const float* query     = (const float*)d_in[0];
    const float* pair      = (const float*)d_in[1];
    const int*   nlist     = (const int*)d_in[2];
    const float* delta_pos = (const float*)d_in[3];
    const float* attn_mask = (const float*)d_in[4];
    const float* ln_g      = (const float*)d_in[5];
    const float* ln_b      = (const float*)d_in[6];
    const float* pn_g      = (const float*)d_in[7];
    const float* pn_b      = (const float*)d_in[8];
    const float* Wq        = (const float*)d_in[9];
    const float* Wk        = (const float*)d_in[10];
    const float* Wv        = (const float*)d_in[11];
    const float* Wbias     = (const float*)d_in[12];
    const float* bbias     = (const float*)d_in[13];
    const float* Wforce    = (const float*)d_in[14];
    float* out  = (float*)d_out;

    float* q_ws = (float*)d_ws;
    float* k_ws = q_ws + (size_t)NROW * EMB;
    float* v_ws = k_ws + (size_t)NROW * EMB;

    qkv_kernel<<<512, 256, 0, stream>>>(query, ln_g, ln_b, Wq, Wk, Wv, q_ws, k_ws, v_ws);
    attn_force_kernel<<<NROW, 256, 0, stream>>>(pair, nlist, delta_pos, attn_mask,
                                                pn_g, pn_b, Wbias, bbias, Wforce,
                                                q_ws, k_ws, v_ws, out);
}

// Round 2
// 277.624 us; speedup vs baseline: 1.4145x; 1.4145x over previous
//
#include <hip/hip_runtime.h>

#define NFR   4
#define NLOCC 2048
#define NNEIN 64
#define EMB   128
#define PDIM  64
#define NH    8
#define LNEPS 1e-5f
#define NROW  (NFR*NLOCC)   // 8192

// workspace layout (float offsets)
#define WS_Q   0
#define WS_K   (NROW*EMB)                    // 1,048,576
#define WS_FV  (2*NROW*EMB)                  // 2,097,152 : fv[row][8]
#define WS_WVF (2*NROW*EMB + NROW*NH)        // 2,162,688 : Wv_f[8][128]
#define WS_G   (WS_WVF + NH*EMB)             // +1024     : G[8][64]
#define WS_SG  (WS_G + NH*PDIM)              // +512      : SG[8] then C[8]

__device__ __forceinline__ void fma4(float4& acc, const float4 a, const float4 b) {
    acc.x = fmaf(a.x, b.x, acc.x);
    acc.y = fmaf(a.y, b.y, acc.y);
    acc.z = fmaf(a.z, b.z, acc.z);
    acc.w = fmaf(a.w, b.w, acc.w);
}
__device__ __forceinline__ void fma4s(float4& acc, const float s, const float4 b) {
    acc.x = fmaf(s, b.x, acc.x);
    acc.y = fmaf(s, b.y, acc.y);
    acc.z = fmaf(s, b.z, acc.z);
    acc.w = fmaf(s, b.w, acc.w);
}
__device__ __forceinline__ float hsum4(const float4 a) {
    return (a.x + a.y) + (a.z + a.w);
}
__device__ __forceinline__ float4 scale4(const float4 a, const float s) {
    return make_float4(a.x*s, a.y*s, a.z*s, a.w*s);
}

// ---------------- Kernel 0: tiny precomputes ----------------
// Wv_f[h][e] = sum_d Wforce[h*16+d]*Wv[(h*16+d)*128+e]  (folds force dot into v proj)
// G[h][p] = pn_g[p]*Wbias[h][p]; SG[h]=sum G; C[h]=sum pn_b*Wbias + bbias
__global__ __launch_bounds__(256) void precompute_kernel(
    const float* __restrict__ pn_g, const float* __restrict__ pn_b,
    const float* __restrict__ Wbias, const float* __restrict__ bbias,
    const float* __restrict__ Wv, const float* __restrict__ Wforce,
    float* __restrict__ ws)
{
    const int t = threadIdx.x;
    {
        const int h  = t >> 5;
        const int e0 = (t & 31) * 4;
        float4 acc = make_float4(0.f, 0.f, 0.f, 0.f);
        #pragma unroll
        for (int d = 0; d < 16; ++d) {
            const float wf = Wforce[h*16 + d];
            const float4 wv = *(const float4*)(Wv + (size_t)(h*16 + d)*EMB + e0);
            fma4s(acc, wf, wv);
        }
        *(float4*)(ws + WS_WVF + (size_t)h*EMB + e0) = acc;
    }
    for (int idx = t; idx < NH*PDIM; idx += 256) {
        const int h = idx >> 6, p = idx & 63;
        ws[WS_G + idx] = pn_g[p] * Wbias[h*PDIM + p];
    }
    if (t < NH) {
        float sg = 0.f, c = 0.f;
        #pragma unroll 8
        for (int p = 0; p < PDIM; ++p) {
            const float wb = Wbias[t*PDIM + p];
            sg = fmaf(pn_g[p], wb, sg);
            c  = fmaf(pn_b[p], wb, c);
        }
        ws[WS_SG + t]      = sg;
        ws[WS_SG + NH + t] = c + bbias[t];
    }
}

// ---------------- Kernel 1: LN(query) + q,k projections + fv ----------------
// 512 blocks x 256 threads, 16 rows/block. W staged through LDS in transposed
// K-tiles (16 e x 132 cols) double-buffered: coalesced 16-line staging loads,
// conflict-free (e+cq)%8 tile reads.
__global__ __launch_bounds__(256, 2) void qkfv_kernel(
    const float* __restrict__ query,
    const float* __restrict__ ln_g, const float* __restrict__ ln_b,
    const float* __restrict__ Wq, const float* __restrict__ Wk,
    float* __restrict__ ws)
{
    __shared__ float gb_s[2][EMB];
    __shared__ float qn_s[16*132];       // padded rows (33 float4/row)
    __shared__ float wt_s[2][16*132];    // [e_local][col] transposed tile, pad 132
    const int t = threadIdx.x;
    const int rowbase = blockIdx.x * 16;

    if (t < 64) {
        const float* src = (t < 32) ? ln_g : ln_b;
        ((float4*)gb_s[t >> 5])[t & 31] = ((const float4*)src)[t & 31];
    }

    // LayerNorm: 16 threads per row, 8 floats each
    const int r   = t >> 4;
    const int seg = t & 15;
    float4 x0 = ((const float4*)query)[(size_t)(rowbase + r)*32 + seg*2 + 0];
    float4 x1 = ((const float4*)query)[(size_t)(rowbase + r)*32 + seg*2 + 1];
    float s  = (x0.x + x0.y) + (x0.z + x0.w) + (x1.x + x1.y) + (x1.z + x1.w);
    float ss = x0.x*x0.x + x0.y*x0.y + x0.z*x0.z + x0.w*x0.w
             + x1.x*x1.x + x1.y*x1.y + x1.z*x1.z + x1.w*x1.w;
    #pragma unroll
    for (int m = 1; m < 16; m <<= 1) {
        s  += __shfl_xor(s,  m, 64);
        ss += __shfl_xor(ss, m, 64);
    }
    const float mean = s * (1.0f / 128.0f);
    const float var  = ss * (1.0f / 128.0f) - mean * mean;
    const float rstd = rsqrtf(var + LNEPS);
    __syncthreads();   // gb_s ready

    {
        const int c0 = seg * 8;
        float4 o0, o1;
        o0.x = (x0.x - mean)*rstd*gb_s[0][c0+0] + gb_s[1][c0+0];
        o0.y = (x0.y - mean)*rstd*gb_s[0][c0+1] + gb_s[1][c0+1];
        o0.z = (x0.z - mean)*rstd*gb_s[0][c0+2] + gb_s[1][c0+2];
        o0.w = (x0.w - mean)*rstd*gb_s[0][c0+3] + gb_s[1][c0+3];
        o1.x = (x1.x - mean)*rstd*gb_s[0][c0+4] + gb_s[1][c0+4];
        o1.y = (x1.y - mean)*rstd*gb_s[0][c0+5] + gb_s[1][c0+5];
        o1.z = (x1.z - mean)*rstd*gb_s[0][c0+6] + gb_s[1][c0+6];
        o1.w = (x1.w - mean)*rstd*gb_s[0][c0+7] + gb_s[1][c0+7];
        ((float4*)qn_s)[r*33 + seg*2 + 0] = o0;
        ((float4*)qn_s)[r*33 + seg*2 + 1] = o1;
    }
    __syncthreads();

    const int rp = t >> 5;        // 0..7 (row pair)
    const int r0 = rp * 2;
    const int cq = t & 31;        // col quad (cols 4cq..4cq+3)
    const int sc0 = t >> 2;       // staging col (0..63)
    const int si0 = t & 3;        // staging e-chunk
    const float4* qn4 = (const float4*)qn_s;

    for (int w = 0; w < 2; ++w) {
        const float4* W4 = (const float4*)((w == 0) ? Wq : Wk);
        float4 acc0 = make_float4(0.f,0.f,0.f,0.f);
        float4 acc1 = make_float4(0.f,0.f,0.f,0.f);
        // prologue: stage tile 0 -> buf 0
        {
            float4 g0 = W4[(size_t)sc0*32 + si0];
            float4 g1 = W4[(size_t)(sc0+64)*32 + si0];
            float* wt = wt_s[0];
            wt[(si0*4+0)*132 + sc0] = g0.x; wt[(si0*4+1)*132 + sc0] = g0.y;
            wt[(si0*4+2)*132 + sc0] = g0.z; wt[(si0*4+3)*132 + sc0] = g0.w;
            wt[(si0*4+0)*132 + sc0+64] = g1.x; wt[(si0*4+1)*132 + sc0+64] = g1.y;
            wt[(si0*4+2)*132 + sc0+64] = g1.z; wt[(si0*4+3)*132 + sc0+64] = g1.w;
        }
        __syncthreads();
        #pragma unroll
        for (int tau = 0; tau < 8; ++tau) {
            const int buf = tau & 1;
            float4 ng0, ng1;
            if (tau < 7) {
                ng0 = W4[(size_t)sc0*32 + (tau+1)*4 + si0];
                ng1 = W4[(size_t)(sc0+64)*32 + (tau+1)*4 + si0];
            }
            const float4* wt4 = (const float4*)wt_s[buf];
            #pragma unroll
            for (int e4 = 0; e4 < 4; ++e4) {
                float4 a0 = qn4[r0*33 + tau*4 + e4];
                float4 a1 = qn4[(r0+1)*33 + tau*4 + e4];
                const float* a0p = (const float*)&a0;
                const float* a1p = (const float*)&a1;
                #pragma unroll
                for (int ee = 0; ee < 4; ++ee) {
                    const float4 wv = wt4[(e4*4+ee)*33 + cq];
                    fma4s(acc0, a0p[ee], wv);
                    fma4s(acc1, a1p[ee], wv);
                }
            }
            if (tau < 7) {
                float* wt = wt_s[buf ^ 1];
                wt[(si0*4+0)*132 + sc0] = ng0.x; wt[(si0*4+1)*132 + sc0] = ng0.y;
                wt[(si0*4+2)*132 + sc0] = ng0.z; wt[(si0*4+3)*132 + sc0] = ng0.w;
                wt[(si0*4+0)*132 + sc0+64] = ng1.x; wt[(si0*4+1)*132 + sc0+64] = ng1.y;
                wt[(si0*4+2)*132 + sc0+64] = ng1.z; wt[(si0*4+3)*132 + sc0+64] = ng1.w;
            }
            __syncthreads();
        }
        const float sc = (w == 0) ? 0.25f : 1.0f;   // HD^-0.5 folded into q
        float4* dst = (float4*)(ws + (w == 0 ? WS_Q : WS_K));
        dst[(size_t)(rowbase + r0)*32 + cq]     = scale4(acc0, sc);
        dst[(size_t)(rowbase + r0 + 1)*32 + cq] = scale4(acc1, sc);
    }

    // fv[row][h] = dot128(qn[row], Wv_f[h])
    if (t < 128) {
        const int rr = t >> 3, h = t & 7;
        const float4* wvf4 = (const float4*)(ws + WS_WVF + (size_t)h*EMB);
        float4 acc = make_float4(0.f,0.f,0.f,0.f);
        #pragma unroll
        for (int ch = 0; ch < 32; ++ch)
            fma4(acc, qn4[rr*33 + ch], wvf4[ch]);
        ws[WS_FV + (size_t)(rowbase + rr)*NH + h] = hsum4(acc);
    }
}

// ---------------- Kernel 2: pair LN + bias + attn + softmax + force ----------------
// 8192 blocks x 256 threads (4 threads/neighbor). K gathered through padded LDS
// (stride 132 floats) with contiguous per-half-wave row reads; bias via folded G.
__global__ __launch_bounds__(256, 4) void attn_force_kernel(
    const float* __restrict__ pair, const int* __restrict__ nlist,
    const float* __restrict__ delta_pos, const float* __restrict__ attn_mask,
    const float* __restrict__ ws, float* __restrict__ out)
{
    __shared__ float4 lds_k4[4*16*33];   // 33792 B: [wave][row 16][33 chunks]
    __shared__ float4 q_s4[32];
    __shared__ float4 G_s4[128];         // G[h][64] head-major
    __shared__ float  csg_s[16];         // SG[0..7], C[8..15]
    __shared__ float  logit_s[NNEIN*9];  // [n][9] stride coprime with 32
    __shared__ float  s_s[NNEIN];
    __shared__ int    nl_s[NNEIN];

    const int t = threadIdx.x;
    const int bid = blockIdx.x;
    const int fr = bid >> 11;
    const int l  = bid & 2047;

    if (t < 16) ((int4*)nl_s)[t] = ((const int4*)(nlist + (size_t)bid*NNEIN))[t];
    __syncthreads();

    // ---- k gather into per-wave LDS region (contiguous 512B row reads) ----
    {
        const int w = t >> 6, lane = t & 63;
        const int half = lane >> 5, c = lane & 31;
        const float4* k4 = (const float4*)(ws + WS_K);
        int jj[8];
        #pragma unroll
        for (int i = 0; i < 8; ++i)
            jj[i] = nl_s[(w << 4) | (i << 1) | half];
        float4 vv[8];
        #pragma unroll
        for (int i = 0; i < 8; ++i)
            vv[i] = k4[((size_t)(fr << 11) + jj[i])*32 + c];
        #pragma unroll
        for (int i = 0; i < 8; ++i)
            lds_k4[(w*16 + ((i << 1) | half))*33 + c] = vv[i];
    }
    // ---- small staging ----
    if (t < 32)        q_s4[t]      = ((const float4*)(ws + WS_Q + (size_t)bid*EMB))[t];
    else if (t < 160)  G_s4[t - 32] = ((const float4*)(ws + WS_G))[t - 32];
    else if (t < 164)  ((float4*)csg_s)[t - 160] = ((const float4*)(ws + WS_SG))[t - 160];
    __syncthreads();

    const int n = t >> 2, sub = t & 3;
    const int w = t >> 6;
    const int h0 = sub*2, h1 = h0 + 1;

    // ---- pair load (per-lane contiguous 64B) + LN stats in registers ----
    const float4* prow = (const float4*)(pair + ((size_t)bid*NNEIN + n)*PDIM);
    float4 pr[4];
    #pragma unroll
    for (int i = 0; i < 4; ++i) pr[i] = prow[sub*4 + i];
    float s = 0.f, ss = 0.f;
    #pragma unroll
    for (int i = 0; i < 4; ++i) {
        s  += (pr[i].x + pr[i].y) + (pr[i].z + pr[i].w);
        ss += pr[i].x*pr[i].x + pr[i].y*pr[i].y + pr[i].z*pr[i].z + pr[i].w*pr[i].w;
    }
    s  += __shfl_xor(s, 1, 64);  s  += __shfl_xor(s, 2, 64);
    ss += __shfl_xor(ss, 1, 64); ss += __shfl_xor(ss, 2, 64);
    const float mean = s * (1.0f / 64.0f);
    const float var  = ss * (1.0f / 64.0f) - mean * mean;
    const float rstd = rsqrtf(var + LNEPS);

    // ---- raw dot d[h] = sum_p x_p * G[h][p]; bias = rstd*(d - mean*SG) + C ----
    float d[NH];
    #pragma unroll
    for (int h = 0; h < NH; ++h) d[h] = 0.f;
    #pragma unroll
    for (int i = 0; i < 4; ++i) {
        const float* xp = (const float*)&pr[i];
        #pragma unroll
        for (int h = 0; h < NH; ++h) {
            const float4 g4 = G_s4[h*16 + sub*4 + i];
            d[h] = fmaf(xp[0], g4.x, d[h]);
            d[h] = fmaf(xp[1], g4.y, d[h]);
            d[h] = fmaf(xp[2], g4.z, d[h]);
            d[h] = fmaf(xp[3], g4.w, d[h]);
        }
    }
    #pragma unroll
    for (int h = 0; h < NH; ++h) {
        d[h] += __shfl_xor(d[h], 1, 64);
        d[h] += __shfl_xor(d[h], 2, 64);
    }

    // ---- QK logits from LDS-staged k (lane's contiguous e-slice [32*sub, +32)) ----
    {
        const int rbase = (w*16 + (n & 15))*33 + 8*sub;
        float4 accA = make_float4(0.f,0.f,0.f,0.f);
        float4 accB = make_float4(0.f,0.f,0.f,0.f);
        #pragma unroll
        for (int j4 = 0; j4 < 4; ++j4) {
            fma4(accA, lds_k4[rbase + j4],     q_s4[8*sub + j4]);
            fma4(accB, lds_k4[rbase + 4 + j4], q_s4[8*sub + 4 + j4]);
        }
        const float m0 = attn_mask[((size_t)(fr*NH + h0)*NLOCC + l)*NNEIN + n];
        const float m1 = attn_mask[((size_t)(fr*NH + h1)*NLOCC + l)*NNEIN + n];
        logit_s[n*9 + h0] = hsum4(accA) + rstd*(d[h0] - mean*csg_s[h0]) + csg_s[8 + h0] + m0;
        logit_s[n*9 + h1] = hsum4(accB) + rstd*(d[h1] - mean*csg_s[h1]) + csg_s[8 + h1] + m1;
    }
    __syncthreads();

    // ---- softmax per head (32 lanes per head), stride-9 conflict-free ----
    {
        const int h = t >> 5, i = t & 31;
        float a = logit_s[i*9 + h], b = logit_s[(i + 32)*9 + h];
        float m = fmaxf(a, b);
        #pragma unroll
        for (int mm = 16; mm >= 1; mm >>= 1) m = fmaxf(m, __shfl_xor(m, mm, 64));
        float ea = __expf(a - m), eb = __expf(b - m);
        float sum = ea + eb;
        #pragma unroll
        for (int mm = 16; mm >= 1; mm >>= 1) sum += __shfl_xor(sum, mm, 64);
        const float inv = 1.0f / sum;
        logit_s[i*9 + h]        = ea * inv;
        logit_s[(i + 32)*9 + h] = eb * inv;
    }
    __syncthreads();

    // ---- s[n] = sum_h probs[n][h] * fv[f,j,h]  (fv = Wforce·v precomputed) ----
    {
        const int j = nl_s[n];
        const float2 fv = ((const float2*)(ws + WS_FV + ((size_t)(fr << 11) + j)*NH))[sub];
        float sn = logit_s[n*9 + h0]*fv.x + logit_s[n*9 + h1]*fv.y;
        sn += __shfl_xor(sn, 1, 64);
        sn += __shfl_xor(sn, 2, 64);
        if (sub == 0) s_s[n] = sn;
    }
    __syncthreads();

    // ---- force[c] = sum_n s[n] * delta_pos[n][c] ----
    if (t < 64) {
        const float sv = s_s[t];
        const float* dp = delta_pos + ((size_t)bid*NNEIN + t)*3;
        float f0 = sv*dp[0], f1 = sv*dp[1], f2 = sv*dp[2];
        #pragma unroll
        for (int mm = 32; mm >= 1; mm >>= 1) {
            f0 += __shfl_xor(f0, mm, 64);
            f1 += __shfl_xor(f1, mm, 64);
            f2 += __shfl_xor(f2, mm, 64);
        }
        if (t == 0) {
            out[(size_t)bid*3 + 0] = f0;
            out[(size_t)bid*3 + 1] = f1;
            out[(size_t)bid*3 + 2] = f2;
        }
    }
}

extern "C" void kernel_launch(void* const* d_in, const int* in_sizes, int n_in,
                              void* d_out, int out_size, void* d_ws, size_t ws_size,
                              hipStream_t stream) {
    const float* query     = (const float*)d_in[0];
    const float* pair      = (const float*)d_in[1];
    const int*   nlist     = (const int*)d_in[2];
    const float* delta_pos = (const float*)d_in[3];
    const float* attn_mask = (const float*)d_in[4];
    const float* ln_g      = (const float*)d_in[5];
    const float* ln_b      = (const float*)d_in[6];
    const float* pn_g      = (const float*)d_in[7];
    const float* pn_b      = (const float*)d_in[8];
    const float* Wq        = (const float*)d_in[9];
    const float* Wk        = (const float*)d_in[10];
    const float* Wv        = (const float*)d_in[11];
    const float* Wbias     = (const float*)d_in[12];
    const float* bbias     = (const float*)d_in[13];
    const float* Wforce    = (const float*)d_in[14];
    float* out = (float*)d_out;
    float* ws  = (float*)d_ws;

    precompute_kernel<<<1, 256, 0, stream>>>(pn_g, pn_b, Wbias, bbias, Wv, Wforce, ws);
    qkfv_kernel<<<512, 256, 0, stream>>>(query, ln_g, ln_b, Wq, Wk, ws);
    attn_force_kernel<<<NROW, 256, 0, stream>>>(pair, nlist, delta_pos, attn_mask, ws, out);
}

// Round 3
// 265.169 us; speedup vs baseline: 1.4809x; 1.0470x over previous
//
#include <hip/hip_runtime.h>

#define NFR   4
#define NLOCC 2048
#define NNEIN 64
#define EMB   128
#define PDIM  64
#define NH    8
#define LNEPS 1e-5f
#define NROW  (NFR*NLOCC)   // 8192

// workspace layout (float offsets)
#define WS_Q   0
#define WS_K   (NROW*EMB)                    // 1,048,576
#define WS_FV  (2*NROW*EMB)                  // 2,097,152 : fv[row][8]
#define WS_WVF (2*NROW*EMB + NROW*NH)        // 2,162,688 : Wv_f[8][128]
#define WS_G   (WS_WVF + NH*EMB)             // +1024     : G[8][64]
#define WS_SG  (WS_G + NH*PDIM)              // +512      : SG[8] then C[8]

__device__ __forceinline__ void fma4(float4& acc, const float4 a, const float4 b) {
    acc.x = fmaf(a.x, b.x, acc.x);
    acc.y = fmaf(a.y, b.y, acc.y);
    acc.z = fmaf(a.z, b.z, acc.z);
    acc.w = fmaf(a.w, b.w, acc.w);
}
__device__ __forceinline__ void fma4s(float4& acc, const float s, const float4 b) {
    acc.x = fmaf(s, b.x, acc.x);
    acc.y = fmaf(s, b.y, acc.y);
    acc.z = fmaf(s, b.z, acc.z);
    acc.w = fmaf(s, b.w, acc.w);
}
__device__ __forceinline__ float hsum4(const float4 a) {
    return (a.x + a.y) + (a.z + a.w);
}
__device__ __forceinline__ float dot4(const float4 a, const float4 b) {
    return fmaf(a.x, b.x, fmaf(a.y, b.y, fmaf(a.z, b.z, a.w * b.w)));
}
__device__ __forceinline__ float4 scale4(const float4 a, const float s) {
    return make_float4(a.x*s, a.y*s, a.z*s, a.w*s);
}

// ---------------- Kernel 0: tiny precomputes ----------------
__global__ __launch_bounds__(256) void precompute_kernel(
    const float* __restrict__ pn_g, const float* __restrict__ pn_b,
    const float* __restrict__ Wbias, const float* __restrict__ bbias,
    const float* __restrict__ Wv, const float* __restrict__ Wforce,
    float* __restrict__ ws)
{
    const int t = threadIdx.x;
    {
        const int h  = t >> 5;
        const int e0 = (t & 31) * 4;
        float4 acc = make_float4(0.f, 0.f, 0.f, 0.f);
        #pragma unroll
        for (int d = 0; d < 16; ++d) {
            const float wf = Wforce[h*16 + d];
            const float4 wv = *(const float4*)(Wv + (size_t)(h*16 + d)*EMB + e0);
            fma4s(acc, wf, wv);
        }
        *(float4*)(ws + WS_WVF + (size_t)h*EMB + e0) = acc;
    }
    for (int idx = t; idx < NH*PDIM; idx += 256) {
        const int h = idx >> 6, p = idx & 63;
        ws[WS_G + idx] = pn_g[p] * Wbias[h*PDIM + p];
    }
    if (t < NH) {
        float sg = 0.f, c = 0.f;
        #pragma unroll 8
        for (int p = 0; p < PDIM; ++p) {
            const float wb = Wbias[t*PDIM + p];
            sg = fmaf(pn_g[p], wb, sg);
            c  = fmaf(pn_b[p], wb, c);
        }
        ws[WS_SG + t]      = sg;
        ws[WS_SG + NH + t] = c + bbias[t];
    }
}

// ---------------- Kernel 1: LN(query) + q,k projections + fv (unchanged) ----------------
__global__ __launch_bounds__(256, 2) void qkfv_kernel(
    const float* __restrict__ query,
    const float* __restrict__ ln_g, const float* __restrict__ ln_b,
    const float* __restrict__ Wq, const float* __restrict__ Wk,
    float* __restrict__ ws)
{
    __shared__ float gb_s[2][EMB];
    __shared__ float qn_s[16*132];
    __shared__ float wt_s[2][16*132];
    const int t = threadIdx.x;
    const int rowbase = blockIdx.x * 16;

    if (t < 64) {
        const float* src = (t < 32) ? ln_g : ln_b;
        ((float4*)gb_s[t >> 5])[t & 31] = ((const float4*)src)[t & 31];
    }

    const int r   = t >> 4;
    const int seg = t & 15;
    float4 x0 = ((const float4*)query)[(size_t)(rowbase + r)*32 + seg*2 + 0];
    float4 x1 = ((const float4*)query)[(size_t)(rowbase + r)*32 + seg*2 + 1];
    float s  = (x0.x + x0.y) + (x0.z + x0.w) + (x1.x + x1.y) + (x1.z + x1.w);
    float ss = x0.x*x0.x + x0.y*x0.y + x0.z*x0.z + x0.w*x0.w
             + x1.x*x1.x + x1.y*x1.y + x1.z*x1.z + x1.w*x1.w;
    #pragma unroll
    for (int m = 1; m < 16; m <<= 1) {
        s  += __shfl_xor(s,  m, 64);
        ss += __shfl_xor(ss, m, 64);
    }
    const float mean = s * (1.0f / 128.0f);
    const float var  = ss * (1.0f / 128.0f) - mean * mean;
    const float rstd = rsqrtf(var + LNEPS);
    __syncthreads();

    {
        const int c0 = seg * 8;
        float4 o0, o1;
        o0.x = (x0.x - mean)*rstd*gb_s[0][c0+0] + gb_s[1][c0+0];
        o0.y = (x0.y - mean)*rstd*gb_s[0][c0+1] + gb_s[1][c0+1];
        o0.z = (x0.z - mean)*rstd*gb_s[0][c0+2] + gb_s[1][c0+2];
        o0.w = (x0.w - mean)*rstd*gb_s[0][c0+3] + gb_s[1][c0+3];
        o1.x = (x1.x - mean)*rstd*gb_s[0][c0+4] + gb_s[1][c0+4];
        o1.y = (x1.y - mean)*rstd*gb_s[0][c0+5] + gb_s[1][c0+5];
        o1.z = (x1.z - mean)*rstd*gb_s[0][c0+6] + gb_s[1][c0+6];
        o1.w = (x1.w - mean)*rstd*gb_s[0][c0+7] + gb_s[1][c0+7];
        ((float4*)qn_s)[r*33 + seg*2 + 0] = o0;
        ((float4*)qn_s)[r*33 + seg*2 + 1] = o1;
    }
    __syncthreads();

    const int rp = t >> 5;
    const int r0 = rp * 2;
    const int cq = t & 31;
    const int sc0 = t >> 2;
    const int si0 = t & 3;
    const float4* qn4 = (const float4*)qn_s;

    for (int w = 0; w < 2; ++w) {
        const float4* W4 = (const float4*)((w == 0) ? Wq : Wk);
        float4 acc0 = make_float4(0.f,0.f,0.f,0.f);
        float4 acc1 = make_float4(0.f,0.f,0.f,0.f);
        {
            float4 g0 = W4[(size_t)sc0*32 + si0];
            float4 g1 = W4[(size_t)(sc0+64)*32 + si0];
            float* wt = wt_s[0];
            wt[(si0*4+0)*132 + sc0] = g0.x; wt[(si0*4+1)*132 + sc0] = g0.y;
            wt[(si0*4+2)*132 + sc0] = g0.z; wt[(si0*4+3)*132 + sc0] = g0.w;
            wt[(si0*4+0)*132 + sc0+64] = g1.x; wt[(si0*4+1)*132 + sc0+64] = g1.y;
            wt[(si0*4+2)*132 + sc0+64] = g1.z; wt[(si0*4+3)*132 + sc0+64] = g1.w;
        }
        __syncthreads();
        #pragma unroll
        for (int tau = 0; tau < 8; ++tau) {
            const int buf = tau & 1;
            float4 ng0, ng1;
            if (tau < 7) {
                ng0 = W4[(size_t)sc0*32 + (tau+1)*4 + si0];
                ng1 = W4[(size_t)(sc0+64)*32 + (tau+1)*4 + si0];
            }
            const float4* wt4 = (const float4*)wt_s[buf];
            #pragma unroll
            for (int e4 = 0; e4 < 4; ++e4) {
                float4 a0 = qn4[r0*33 + tau*4 + e4];
                float4 a1 = qn4[(r0+1)*33 + tau*4 + e4];
                const float* a0p = (const float*)&a0;
                const float* a1p = (const float*)&a1;
                #pragma unroll
                for (int ee = 0; ee < 4; ++ee) {
                    const float4 wv = wt4[(e4*4+ee)*33 + cq];
                    fma4s(acc0, a0p[ee], wv);
                    fma4s(acc1, a1p[ee], wv);
                }
            }
            if (tau < 7) {
                float* wt = wt_s[buf ^ 1];
                wt[(si0*4+0)*132 + sc0] = ng0.x; wt[(si0*4+1)*132 + sc0] = ng0.y;
                wt[(si0*4+2)*132 + sc0] = ng0.z; wt[(si0*4+3)*132 + sc0] = ng0.w;
                wt[(si0*4+0)*132 + sc0+64] = ng1.x; wt[(si0*4+1)*132 + sc0+64] = ng1.y;
                wt[(si0*4+2)*132 + sc0+64] = ng1.z; wt[(si0*4+3)*132 + sc0+64] = ng1.w;
            }
            __syncthreads();
        }
        const float sc = (w == 0) ? 0.25f : 1.0f;
        float4* dst = (float4*)(ws + (w == 0 ? WS_Q : WS_K));
        dst[(size_t)(rowbase + r0)*32 + cq]     = scale4(acc0, sc);
        dst[(size_t)(rowbase + r0 + 1)*32 + cq] = scale4(acc1, sc);
    }

    if (t < 128) {
        const int rr = t >> 3, h = t & 7;
        const float4* wvf4 = (const float4*)(ws + WS_WVF + (size_t)h*EMB);
        float4 acc = make_float4(0.f,0.f,0.f,0.f);
        #pragma unroll
        for (int ch = 0; ch < 32; ++ch)
            fma4(acc, qn4[rr*33 + ch], wvf4[ch]);
        ws[WS_FV + (size_t)(rowbase + rr)*NH + h] = hsum4(acc);
    }
}

// ---------------- Kernel 2: register-resident attn + force ----------------
// 8192 blocks x 256 threads. No k LDS staging: coalesced gather into registers,
// per-head partials reduced via quad shfl. Softmax+PV+force fused in one phase.
// LDS ~5KB, 3 barriers.
__global__ __launch_bounds__(256, 4) void attn_force_kernel(
    const float* __restrict__ pair, const int* __restrict__ nlist,
    const float* __restrict__ delta_pos, const float* __restrict__ attn_mask,
    const float* __restrict__ ws, float* __restrict__ out)
{
    __shared__ float  logit_s[NNEIN*9];   // [n][9] stride coprime with 32
    __shared__ float4 G_s4[128];          // G[8][64] head-major (2KB)
    __shared__ float  fpart[4][3];

    const int t    = threadIdx.x;
    const int bid  = blockIdx.x;
    const int fr   = bid >> 11;
    const int l    = bid & 2047;
    const int w    = t >> 6;
    const int lane = t & 63;
    const int half = lane >> 5;       // gather mapping
    const int c    = lane & 31;       // k chunk index
    const int n    = (w << 4) | (lane >> 2);   // pair mapping neighbor
    const int sub  = lane & 3;
    const int h0   = sub * 2, h1 = h0 + 1;
    const int i32  = lane & 31;       // softmax row index
    const int hh   = (w << 1) | half; // softmax head (== t>>5)

    // ---------------- early independent loads ----------------
    const float4* prow = (const float4*)(pair + ((size_t)bid*NNEIN + n)*PDIM);
    float4 pr0 = prow[sub*4+0];
    float4 pr1 = prow[sub*4+1];
    float4 pr2 = prow[sub*4+2];
    float4 pr3 = prow[sub*4+3];

    const int jv = nlist[(size_t)bid*NNEIN + lane];                    // full row/lane
    const float4 q4c = ((const float4*)(ws + WS_Q))[(size_t)bid*32 + c];

    const float mask0 = attn_mask[((size_t)(fr*NH + h0)*NLOCC + l)*NNEIN + n];
    const float mask1 = attn_mask[((size_t)(fr*NH + h1)*NLOCC + l)*NNEIN + n];
    const float sg0 = ws[WS_SG + h0],      sg1 = ws[WS_SG + h1];
    const float cc0 = ws[WS_SG + NH + h0], cc1 = ws[WS_SG + NH + h1];

    const float* dpA = delta_pos + ((size_t)bid*NNEIN + i32)*3;
    const float* dpB = delta_pos + ((size_t)bid*NNEIN + i32 + 32)*3;
    const float dpax = dpA[0], dpay = dpA[1], dpaz = dpA[2];
    const float dpbx = dpB[0], dpby = dpB[1], dpbz = dpB[2];

    if (t < 128) G_s4[t] = ((const float4*)(ws + WS_G))[t];

    // fv gather (softmax mapping), prefetched
    const int jA = __shfl(jv, i32, 64);
    const int jB = __shfl(jv, i32 + 32, 64);
    const float fvA = ws[WS_FV + ((size_t)(fr << 11) + jA)*NH + hh];
    const float fvB = ws[WS_FV + ((size_t)(fr << 11) + jB)*NH + hh];

    // ---------------- QK gather + raw logits ----------------
    {
        const float4* k4 = (const float4*)(ws + WS_K) + (size_t)(fr << 11)*32;
        int jr[8];
        #pragma unroll
        for (int i = 0; i < 8; ++i)
            jr[i] = __shfl(jv, (w << 4) | (i << 1) | half, 64);
        float4 kkA[4], kkB[4];
        #pragma unroll
        for (int i = 0; i < 4; ++i) kkA[i] = k4[(size_t)jr[i]*32 + c];
        #pragma unroll
        for (int i = 0; i < 4; ++i) kkB[i] = k4[(size_t)jr[4+i]*32 + c];
        float p[8];
        #pragma unroll
        for (int i = 0; i < 4; ++i) p[i]     = dot4(kkA[i], q4c);
        #pragma unroll
        for (int i = 0; i < 4; ++i) p[4 + i] = dot4(kkB[i], q4c);
        #pragma unroll
        for (int i = 0; i < 8; ++i) {
            float pp = p[i];
            pp += __shfl_xor(pp, 1, 64);
            pp += __shfl_xor(pp, 2, 64);
            if ((c & 3) == 0)
                logit_s[((w << 4) | (i << 1) | half)*9 + (c >> 2)] = pp;
        }
    }
    __syncthreads();   // (1) raw logits + G staged

    // ---------------- pair LN + bias, RMW into logits ----------------
    {
        float s  = hsum4(pr0) + hsum4(pr1) + hsum4(pr2) + hsum4(pr3);
        float ss = dot4(pr0, pr0) + dot4(pr1, pr1) + dot4(pr2, pr2) + dot4(pr3, pr3);
        s  += __shfl_xor(s, 1, 64);  s  += __shfl_xor(s, 2, 64);
        ss += __shfl_xor(ss, 1, 64); ss += __shfl_xor(ss, 2, 64);
        const float mean = s * (1.0f / 64.0f);
        const float var  = ss * (1.0f / 64.0f) - mean * mean;
        const float rstd = rsqrtf(var + LNEPS);

        float d[NH];
        #pragma unroll
        for (int h = 0; h < NH; ++h) d[h] = 0.f;
        const float4 prq[4] = {pr0, pr1, pr2, pr3};
        #pragma unroll
        for (int q = 0; q < 4; ++q) {
            #pragma unroll
            for (int h = 0; h < NH; ++h)
                d[h] += dot4(prq[q], G_s4[h*16 + sub*4 + q]);
        }
        #pragma unroll
        for (int h = 0; h < NH; ++h) {
            d[h] += __shfl_xor(d[h], 1, 64);
            d[h] += __shfl_xor(d[h], 2, 64);
        }
        const float b0 = rstd*(d[h0] - mean*sg0) + cc0 + mask0;
        const float b1 = rstd*(d[h1] - mean*sg1) + cc1 + mask1;
        logit_s[n*9 + h0] += b0;
        logit_s[n*9 + h1] += b1;
    }
    __syncthreads();   // (2)

    // ---------------- softmax + PV + force (fused, softmax mapping) ----------------
    {
        float a = logit_s[i32*9 + hh], b = logit_s[(i32 + 32)*9 + hh];
        float m = fmaxf(a, b);
        #pragma unroll
        for (int mm = 16; mm >= 1; mm >>= 1) m = fmaxf(m, __shfl_xor(m, mm, 64));
        float ea = __expf(a - m), eb = __expf(b - m);
        float sum = ea + eb;
        #pragma unroll
        for (int mm = 16; mm >= 1; mm >>= 1) sum += __shfl_xor(sum, mm, 64);
        const float inv = 1.0f / sum;
        float ca = ea * inv * fvA;     // prob(row i32, head hh) * fv
        float cb = eb * inv * fvB;     // prob(row i32+32, head hh) * fv
        ca += __shfl_xor(ca, 32, 64);  // + other head of this wave's pair
        cb += __shfl_xor(cb, 32, 64);
        float f0 = ca*dpax + cb*dpbx;
        float f1 = ca*dpay + cb*dpby;
        float f2 = ca*dpaz + cb*dpbz;
        #pragma unroll
        for (int mm = 1; mm <= 16; mm <<= 1) {
            f0 += __shfl_xor(f0, mm, 64);
            f1 += __shfl_xor(f1, mm, 64);
            f2 += __shfl_xor(f2, mm, 64);
        }
        if (lane == 0) {
            fpart[w][0] = f0; fpart[w][1] = f1; fpart[w][2] = f2;
        }
    }
    __syncthreads();   // (3)

    if (t < 3)
        out[(size_t)bid*3 + t] = fpart[0][t] + fpart[1][t] + fpart[2][t] + fpart[3][t];
}

extern "C" void kernel_launch(void* const* d_in, const int* in_sizes, int n_in,
                              void* d_out, int out_size, void* d_ws, size_t ws_size,
                              hipStream_t stream) {
    const float* query     = (const float*)d_in[0];
    const float* pair      = (const float*)d_in[1];
    const int*   nlist     = (const int*)d_in[2];
    const float* delta_pos = (const float*)d_in[3];
    const float* attn_mask = (const float*)d_in[4];
    const float* ln_g      = (const float*)d_in[5];
    const float* ln_b      = (const float*)d_in[6];
    const float* pn_g      = (const float*)d_in[7];
    const float* pn_b      = (const float*)d_in[8];
    const float* Wq        = (const float*)d_in[9];
    const float* Wk        = (const float*)d_in[10];
    const float* Wv        = (const float*)d_in[11];
    const float* Wbias     = (const float*)d_in[12];
    const float* bbias     = (const float*)d_in[13];
    const float* Wforce    = (const float*)d_in[14];
    float* out = (float*)d_out;
    float* ws  = (float*)d_ws;

    precompute_kernel<<<1, 256, 0, stream>>>(pn_g, pn_b, Wbias, bbias, Wv, Wforce, ws);
    qkfv_kernel<<<512, 256, 0, stream>>>(query, ln_g, ln_b, Wq, Wk, ws);
    attn_force_kernel<<<NROW, 256, 0, stream>>>(pair, nlist, delta_pos, attn_mask, ws, out);
}

// Round 4
// 260.020 us; speedup vs baseline: 1.5102x; 1.0198x over previous
//
#include <hip/hip_runtime.h>

#define NFR   4
#define NLOCC 2048
#define NNEIN 64
#define EMB   128
#define PDIM  64
#define NH    8
#define LNEPS 1e-5f
#define NROW  (NFR*NLOCC)   // 8192

// workspace layout (float offsets)
#define WS_Q   0
#define WS_K   (NROW*EMB)                    // 1,048,576
#define WS_FV  (2*NROW*EMB)                  // 2,097,152 : fv[row][8]
#define WS_WVF (2*NROW*EMB + NROW*NH)        // 2,162,688 : Wv_f[8][128]
#define WS_G   (WS_WVF + NH*EMB)             // +1024     : G[8][64]
#define WS_SG  (WS_G + NH*PDIM)              // +512      : SG[8] then C[8]

__device__ __forceinline__ void fma4(float4& acc, const float4 a, const float4 b) {
    acc.x = fmaf(a.x, b.x, acc.x);
    acc.y = fmaf(a.y, b.y, acc.y);
    acc.z = fmaf(a.z, b.z, acc.z);
    acc.w = fmaf(a.w, b.w, acc.w);
}
__device__ __forceinline__ void fma4s(float4& acc, const float s, const float4 b) {
    acc.x = fmaf(s, b.x, acc.x);
    acc.y = fmaf(s, b.y, acc.y);
    acc.z = fmaf(s, b.z, acc.z);
    acc.w = fmaf(s, b.w, acc.w);
}
__device__ __forceinline__ float hsum4(const float4 a) {
    return (a.x + a.y) + (a.z + a.w);
}
__device__ __forceinline__ float dot4(const float4 a, const float4 b) {
    return fmaf(a.x, b.x, fmaf(a.y, b.y, fmaf(a.z, b.z, a.w * b.w)));
}
__device__ __forceinline__ float4 scale4(const float4 a, const float s) {
    return make_float4(a.x*s, a.y*s, a.z*s, a.w*s);
}

// ---------------- Kernel 0: tiny precomputes (unchanged) ----------------
__global__ __launch_bounds__(256) void precompute_kernel(
    const float* __restrict__ pn_g, const float* __restrict__ pn_b,
    const float* __restrict__ Wbias, const float* __restrict__ bbias,
    const float* __restrict__ Wv, const float* __restrict__ Wforce,
    float* __restrict__ ws)
{
    const int t = threadIdx.x;
    {
        const int h  = t >> 5;
        const int e0 = (t & 31) * 4;
        float4 acc = make_float4(0.f, 0.f, 0.f, 0.f);
        #pragma unroll
        for (int d = 0; d < 16; ++d) {
            const float wf = Wforce[h*16 + d];
            const float4 wv = *(const float4*)(Wv + (size_t)(h*16 + d)*EMB + e0);
            fma4s(acc, wf, wv);
        }
        *(float4*)(ws + WS_WVF + (size_t)h*EMB + e0) = acc;
    }
    for (int idx = t; idx < NH*PDIM; idx += 256) {
        const int h = idx >> 6, p = idx & 63;
        ws[WS_G + idx] = pn_g[p] * Wbias[h*PDIM + p];
    }
    if (t < NH) {
        float sg = 0.f, c = 0.f;
        #pragma unroll 8
        for (int p = 0; p < PDIM; ++p) {
            const float wb = Wbias[t*PDIM + p];
            sg = fmaf(pn_g[p], wb, sg);
            c  = fmaf(pn_b[p], wb, c);
        }
        ws[WS_SG + t]      = sg;
        ws[WS_SG + NH + t] = c + bbias[t];
    }
}

// ---------------- Kernel 1: LN(query) + q,k projections + fv (unchanged) ----------------
__global__ __launch_bounds__(256, 2) void qkfv_kernel(
    const float* __restrict__ query,
    const float* __restrict__ ln_g, const float* __restrict__ ln_b,
    const float* __restrict__ Wq, const float* __restrict__ Wk,
    float* __restrict__ ws)
{
    __shared__ float gb_s[2][EMB];
    __shared__ float qn_s[16*132];
    __shared__ float wt_s[2][16*132];
    const int t = threadIdx.x;
    const int rowbase = blockIdx.x * 16;

    if (t < 64) {
        const float* src = (t < 32) ? ln_g : ln_b;
        ((float4*)gb_s[t >> 5])[t & 31] = ((const float4*)src)[t & 31];
    }

    const int r   = t >> 4;
    const int seg = t & 15;
    float4 x0 = ((const float4*)query)[(size_t)(rowbase + r)*32 + seg*2 + 0];
    float4 x1 = ((const float4*)query)[(size_t)(rowbase + r)*32 + seg*2 + 1];
    float s  = (x0.x + x0.y) + (x0.z + x0.w) + (x1.x + x1.y) + (x1.z + x1.w);
    float ss = x0.x*x0.x + x0.y*x0.y + x0.z*x0.z + x0.w*x0.w
             + x1.x*x1.x + x1.y*x1.y + x1.z*x1.z + x1.w*x1.w;
    #pragma unroll
    for (int m = 1; m < 16; m <<= 1) {
        s  += __shfl_xor(s,  m, 64);
        ss += __shfl_xor(ss, m, 64);
    }
    const float mean = s * (1.0f / 128.0f);
    const float var  = ss * (1.0f / 128.0f) - mean * mean;
    const float rstd = rsqrtf(var + LNEPS);
    __syncthreads();

    {
        const int c0 = seg * 8;
        float4 o0, o1;
        o0.x = (x0.x - mean)*rstd*gb_s[0][c0+0] + gb_s[1][c0+0];
        o0.y = (x0.y - mean)*rstd*gb_s[0][c0+1] + gb_s[1][c0+1];
        o0.z = (x0.z - mean)*rstd*gb_s[0][c0+2] + gb_s[1][c0+2];
        o0.w = (x0.w - mean)*rstd*gb_s[0][c0+3] + gb_s[1][c0+3];
        o1.x = (x1.x - mean)*rstd*gb_s[0][c0+4] + gb_s[1][c0+4];
        o1.y = (x1.y - mean)*rstd*gb_s[0][c0+5] + gb_s[1][c0+5];
        o1.z = (x1.z - mean)*rstd*gb_s[0][c0+6] + gb_s[1][c0+6];
        o1.w = (x1.w - mean)*rstd*gb_s[0][c0+7] + gb_s[1][c0+7];
        ((float4*)qn_s)[r*33 + seg*2 + 0] = o0;
        ((float4*)qn_s)[r*33 + seg*2 + 1] = o1;
    }
    __syncthreads();

    const int rp = t >> 5;
    const int r0 = rp * 2;
    const int cq = t & 31;
    const int sc0 = t >> 2;
    const int si0 = t & 3;
    const float4* qn4 = (const float4*)qn_s;

    for (int w = 0; w < 2; ++w) {
        const float4* W4 = (const float4*)((w == 0) ? Wq : Wk);
        float4 acc0 = make_float4(0.f,0.f,0.f,0.f);
        float4 acc1 = make_float4(0.f,0.f,0.f,0.f);
        {
            float4 g0 = W4[(size_t)sc0*32 + si0];
            float4 g1 = W4[(size_t)(sc0+64)*32 + si0];
            float* wt = wt_s[0];
            wt[(si0*4+0)*132 + sc0] = g0.x; wt[(si0*4+1)*132 + sc0] = g0.y;
            wt[(si0*4+2)*132 + sc0] = g0.z; wt[(si0*4+3)*132 + sc0] = g0.w;
            wt[(si0*4+0)*132 + sc0+64] = g1.x; wt[(si0*4+1)*132 + sc0+64] = g1.y;
            wt[(si0*4+2)*132 + sc0+64] = g1.z; wt[(si0*4+3)*132 + sc0+64] = g1.w;
        }
        __syncthreads();
        #pragma unroll
        for (int tau = 0; tau < 8; ++tau) {
            const int buf = tau & 1;
            float4 ng0, ng1;
            if (tau < 7) {
                ng0 = W4[(size_t)sc0*32 + (tau+1)*4 + si0];
                ng1 = W4[(size_t)(sc0+64)*32 + (tau+1)*4 + si0];
            }
            const float4* wt4 = (const float4*)wt_s[buf];
            #pragma unroll
            for (int e4 = 0; e4 < 4; ++e4) {
                float4 a0 = qn4[r0*33 + tau*4 + e4];
                float4 a1 = qn4[(r0+1)*33 + tau*4 + e4];
                const float* a0p = (const float*)&a0;
                const float* a1p = (const float*)&a1;
                #pragma unroll
                for (int ee = 0; ee < 4; ++ee) {
                    const float4 wv = wt4[(e4*4+ee)*33 + cq];
                    fma4s(acc0, a0p[ee], wv);
                    fma4s(acc1, a1p[ee], wv);
                }
            }
            if (tau < 7) {
                float* wt = wt_s[buf ^ 1];
                wt[(si0*4+0)*132 + sc0] = ng0.x; wt[(si0*4+1)*132 + sc0] = ng0.y;
                wt[(si0*4+2)*132 + sc0] = ng0.z; wt[(si0*4+3)*132 + sc0] = ng0.w;
                wt[(si0*4+0)*132 + sc0+64] = ng1.x; wt[(si0*4+1)*132 + sc0+64] = ng1.y;
                wt[(si0*4+2)*132 + sc0+64] = ng1.z; wt[(si0*4+3)*132 + sc0+64] = ng1.w;
            }
            __syncthreads();
        }
        const float sc = (w == 0) ? 0.25f : 1.0f;
        float4* dst = (float4*)(ws + (w == 0 ? WS_Q : WS_K));
        dst[(size_t)(rowbase + r0)*32 + cq]     = scale4(acc0, sc);
        dst[(size_t)(rowbase + r0 + 1)*32 + cq] = scale4(acc1, sc);
    }

    if (t < 128) {
        const int rr = t >> 3, h = t & 7;
        const float4* wvf4 = (const float4*)(ws + WS_WVF + (size_t)h*EMB);
        float4 acc = make_float4(0.f,0.f,0.f,0.f);
        #pragma unroll
        for (int ch = 0; ch < 32; ++ch)
            fma4(acc, qn4[rr*33 + ch], wvf4[ch]);
        ws[WS_FV + (size_t)(rowbase + rr)*NH + h] = hsum4(acc);
    }
}

// ---------------- Kernel 2: TA-minimized attn + force ----------------
// 8192 blocks x 256 threads. Coalesced pair load -> padded LDS tile -> n-mapping
// compute. fv read as float2 in n-mapping (4 lanes cover a row). Softmax writes
// probs back; short n-mapping PV+force phase. 4 barriers, ~23 KB LDS.
__global__ __launch_bounds__(256, 4) void attn_force_kernel(
    const float* __restrict__ pair, const int* __restrict__ nlist,
    const float* __restrict__ delta_pos, const float* __restrict__ attn_mask,
    const float* __restrict__ ws, float* __restrict__ out)
{
    __shared__ float4 pair_s4[64*17];     // 17408 B, padded rows (17 float4)
    __shared__ float  logit_s[NNEIN*9];   // [n][9] stride coprime with 32
    __shared__ float4 G_s4[128];          // G[8][64] head-major (2KB)
    __shared__ float  dp_s[192];          // delta_pos rows for this loc
    __shared__ float  fpart[4][3];

    const int t    = threadIdx.x;
    const int bid  = blockIdx.x;
    const int fr   = bid >> 11;
    const int l    = bid & 2047;
    const int w    = t >> 6;
    const int lane = t & 63;
    const int half = lane >> 5;        // gather mapping
    const int c    = lane & 31;        // k chunk index
    const int n    = t >> 2;           // n-mapping neighbor
    const int sub  = t & 3;
    const int h0   = sub * 2, h1 = h0 + 1;
    const int i32  = lane & 31;        // softmax row index
    const int hh   = t >> 5;           // softmax head

    // ---------------- early independent loads (all coalesced) ----------------
    {
        const float4* p4 = (const float4*)pair + (size_t)bid*1024;
        #pragma unroll
        for (int i = 0; i < 4; ++i) {
            const int ci   = i*256 + t;
            const float4 v = p4[ci];
            pair_s4[(ci >> 4)*17 + (ci & 15)] = v;
        }
    }
    const int jv = nlist[(size_t)bid*NNEIN + lane];   // every wave holds full nlist
    const float4 q4c = ((const float4*)(ws + WS_Q))[(size_t)bid*32 + c];

    const float mask0 = attn_mask[((size_t)(fr*NH + h0)*NLOCC + l)*NNEIN + n];
    const float mask1 = attn_mask[((size_t)(fr*NH + h1)*NLOCC + l)*NNEIN + n];
    const float sg0 = ws[WS_SG + h0],      sg1 = ws[WS_SG + h1];
    const float cc0 = ws[WS_SG + NH + h0], cc1 = ws[WS_SG + NH + h1];

    if (t < 128) G_s4[t] = ((const float4*)(ws + WS_G))[t];
    if (t < 48)  ((float4*)dp_s)[t] = ((const float4*)(delta_pos + (size_t)bid*192))[t];

    // fv: float2 per (n,sub) — 4 lanes cover one 32B fv row
    const int    jn  = __shfl(jv, n & 63, 64);
    const float2 fv2 = ((const float2*)(ws + WS_FV + ((size_t)(fr << 11) + jn)*NH))[sub];

    // ---------------- QK gather + raw logits (gather mapping) ----------------
    {
        const float4* k4 = (const float4*)(ws + WS_K) + (size_t)(fr << 11)*32;
        int jr[8];
        #pragma unroll
        for (int i = 0; i < 8; ++i)
            jr[i] = __shfl(jv, (w << 4) | (i << 1) | half, 64);
        float4 kkA[4], kkB[4];
        #pragma unroll
        for (int i = 0; i < 4; ++i) kkA[i] = k4[(size_t)jr[i]*32 + c];
        #pragma unroll
        for (int i = 0; i < 4; ++i) kkB[i] = k4[(size_t)jr[4+i]*32 + c];
        float p[8];
        #pragma unroll
        for (int i = 0; i < 4; ++i) p[i]     = dot4(kkA[i], q4c);
        #pragma unroll
        for (int i = 0; i < 4; ++i) p[4 + i] = dot4(kkB[i], q4c);
        #pragma unroll
        for (int i = 0; i < 8; ++i) {
            float pp = p[i];
            pp += __shfl_xor(pp, 1, 64);
            pp += __shfl_xor(pp, 2, 64);
            if ((c & 3) == 0)
                logit_s[((w << 4) | (i << 1) | half)*9 + (c >> 2)] = pp;
        }
    }
    __syncthreads();   // (1) pair tile + raw logits + G + dp staged

    // ---------------- pair LN + bias, RMW into logits (n-mapping) ----------------
    {
        const float4 pr0 = pair_s4[n*17 + sub*4 + 0];
        const float4 pr1 = pair_s4[n*17 + sub*4 + 1];
        const float4 pr2 = pair_s4[n*17 + sub*4 + 2];
        const float4 pr3 = pair_s4[n*17 + sub*4 + 3];
        float s  = hsum4(pr0) + hsum4(pr1) + hsum4(pr2) + hsum4(pr3);
        float ss = dot4(pr0, pr0) + dot4(pr1, pr1) + dot4(pr2, pr2) + dot4(pr3, pr3);
        s  += __shfl_xor(s, 1, 64);  s  += __shfl_xor(s, 2, 64);
        ss += __shfl_xor(ss, 1, 64); ss += __shfl_xor(ss, 2, 64);
        const float mean = s * (1.0f / 64.0f);
        const float var  = ss * (1.0f / 64.0f) - mean * mean;
        const float rstd = rsqrtf(var + LNEPS);

        float d[NH];
        #pragma unroll
        for (int h = 0; h < NH; ++h) d[h] = 0.f;
        const float4 prq[4] = {pr0, pr1, pr2, pr3};
        #pragma unroll
        for (int q = 0; q < 4; ++q) {
            #pragma unroll
            for (int h = 0; h < NH; ++h)
                d[h] += dot4(prq[q], G_s4[h*16 + sub*4 + q]);
        }
        #pragma unroll
        for (int h = 0; h < NH; ++h) {
            d[h] += __shfl_xor(d[h], 1, 64);
            d[h] += __shfl_xor(d[h], 2, 64);
        }
        const float b0 = rstd*(d[h0] - mean*sg0) + cc0 + mask0;
        const float b1 = rstd*(d[h1] - mean*sg1) + cc1 + mask1;
        logit_s[n*9 + h0] += b0;
        logit_s[n*9 + h1] += b1;
    }
    __syncthreads();   // (2)

    // ---------------- softmax (hh/i32 mapping), probs back to LDS ----------------
    {
        float a = logit_s[i32*9 + hh], b = logit_s[(i32 + 32)*9 + hh];
        float m = fmaxf(a, b);
        #pragma unroll
        for (int mm = 16; mm >= 1; mm >>= 1) m = fmaxf(m, __shfl_xor(m, mm, 64));
        float ea = __expf(a - m), eb = __expf(b - m);
        float sum = ea + eb;
        #pragma unroll
        for (int mm = 16; mm >= 1; mm >>= 1) sum += __shfl_xor(sum, mm, 64);
        const float inv = 1.0f / sum;
        logit_s[i32*9 + hh]        = ea * inv;
        logit_s[(i32 + 32)*9 + hh] = eb * inv;
    }
    __syncthreads();   // (3)

    // ---------------- PV + force (n-mapping) ----------------
    {
        const float p0 = logit_s[n*9 + h0];
        const float p1 = logit_s[n*9 + h1];
        float sn = p0*fv2.x + p1*fv2.y;
        sn += __shfl_xor(sn, 1, 64);
        sn += __shfl_xor(sn, 2, 64);          // all 4 subs hold s[n]
        float fc = (sub < 3) ? sn * dp_s[n*3 + sub] : 0.f;
        #pragma unroll
        for (int mm = 4; mm <= 32; mm <<= 1)
            fc += __shfl_xor(fc, mm, 64);     // sum over this wave's 16 neighbors
        if (lane < 3) fpart[w][lane] = fc;
    }
    __syncthreads();   // (4)

    if (t < 3)
        out[(size_t)bid*3 + t] = fpart[0][t] + fpart[1][t] + fpart[2][t] + fpart[3][t];
}

extern "C" void kernel_launch(void* const* d_in, const int* in_sizes, int n_in,
                              void* d_out, int out_size, void* d_ws, size_t ws_size,
                              hipStream_t stream) {
    const float* query     = (const float*)d_in[0];
    const float* pair      = (const float*)d_in[1];
    const int*   nlist     = (const int*)d_in[2];
    const float* delta_pos = (const float*)d_in[3];
    const float* attn_mask = (const float*)d_in[4];
    const float* ln_g      = (const float*)d_in[5];
    const float* ln_b      = (const float*)d_in[6];
    const float* pn_g      = (const float*)d_in[7];
    const float* pn_b      = (const float*)d_in[8];
    const float* Wq        = (const float*)d_in[9];
    const float* Wk        = (const float*)d_in[10];
    const float* Wv        = (const float*)d_in[11];
    const float* Wbias     = (const float*)d_in[12];
    const float* bbias     = (const float*)d_in[13];
    const float* Wforce    = (const float*)d_in[14];
    float* out = (float*)d_out;
    float* ws  = (float*)d_ws;

    precompute_kernel<<<1, 256, 0, stream>>>(pn_g, pn_b, Wbias, bbias, Wv, Wforce, ws);
    qkfv_kernel<<<512, 256, 0, stream>>>(query, ln_g, ln_b, Wq, Wk, ws);
    attn_force_kernel<<<NROW, 256, 0, stream>>>(pair, nlist, delta_pos, attn_mask, ws, out);
}

// Round 5
// 253.458 us; speedup vs baseline: 1.5493x; 1.0259x over previous
//
#include <hip/hip_runtime.h>

#define NFR   4
#define NLOCC 2048
#define NNEIN 64
#define EMB   128
#define PDIM  64
#define NH    8
#define LNEPS 1e-5f
#define NROW  (NFR*NLOCC)   // 8192

// workspace layout (float offsets)
#define WS_Q   0
#define WS_K   (NROW*EMB)        // 1,048,576
#define WS_FV  (2*NROW*EMB)      // 2,097,152 : fv[row][8]

__device__ __forceinline__ void fma4(float4& acc, const float4 a, const float4 b) {
    acc.x = fmaf(a.x, b.x, acc.x);
    acc.y = fmaf(a.y, b.y, acc.y);
    acc.z = fmaf(a.z, b.z, acc.z);
    acc.w = fmaf(a.w, b.w, acc.w);
}
__device__ __forceinline__ void fma4s(float4& acc, const float s, const float4 b) {
    acc.x = fmaf(s, b.x, acc.x);
    acc.y = fmaf(s, b.y, acc.y);
    acc.z = fmaf(s, b.z, acc.z);
    acc.w = fmaf(s, b.w, acc.w);
}
__device__ __forceinline__ float hsum4(const float4 a) {
    return (a.x + a.y) + (a.z + a.w);
}
__device__ __forceinline__ float dot4(const float4 a, const float4 b) {
    return fmaf(a.x, b.x, fmaf(a.y, b.y, fmaf(a.z, b.z, a.w * b.w)));
}
__device__ __forceinline__ float4 scale4(const float4 a, const float s) {
    return make_float4(a.x*s, a.y*s, a.z*s, a.w*s);
}

// ---------------- Kernel 1: LN(query) + q,k projections + fv ----------------
// 512 blocks x 256 threads, 16 rows/block. Wv_f = Wforce·Wv computed in-block
// (padded LDS, conflict-free fv reads). W staged in transposed double-buffered
// LDS tiles as before.
__global__ __launch_bounds__(256, 2) void qkfv_kernel(
    const float* __restrict__ query,
    const float* __restrict__ ln_g, const float* __restrict__ ln_b,
    const float* __restrict__ Wq, const float* __restrict__ Wk,
    const float* __restrict__ Wv, const float* __restrict__ Wforce,
    float* __restrict__ ws)
{
    __shared__ float  gb_s[2][EMB];
    __shared__ float  qn_s[16*132];
    __shared__ float  wt_s[2][16*132];
    __shared__ float4 wvf_s4[8*33];      // Wv_f[h][ch], padded rows (33 float4)
    const int t = threadIdx.x;
    const int rowbase = blockIdx.x * 16;

    if (t < 64) {
        const float* src = (t < 32) ? ln_g : ln_b;
        ((float4*)gb_s[t >> 5])[t & 31] = ((const float4*)src)[t & 31];
    }

    // Wv_f[h][e] = sum_d Wforce[h*16+d] * Wv[h*16+d][e]  (one float4/thread)
    {
        const int h = t >> 5, ch = t & 31;
        float4 acc = make_float4(0.f, 0.f, 0.f, 0.f);
        #pragma unroll
        for (int d = 0; d < 16; ++d) {
            const float wf = Wforce[h*16 + d];
            const float4 wv = ((const float4*)(Wv + (size_t)(h*16 + d)*EMB))[ch];
            fma4s(acc, wf, wv);
        }
        wvf_s4[h*33 + ch] = acc;
    }

    // LayerNorm: 16 threads per row, 8 floats each
    const int r   = t >> 4;
    const int seg = t & 15;
    float4 x0 = ((const float4*)query)[(size_t)(rowbase + r)*32 + seg*2 + 0];
    float4 x1 = ((const float4*)query)[(size_t)(rowbase + r)*32 + seg*2 + 1];
    float s  = (x0.x + x0.y) + (x0.z + x0.w) + (x1.x + x1.y) + (x1.z + x1.w);
    float ss = x0.x*x0.x + x0.y*x0.y + x0.z*x0.z + x0.w*x0.w
             + x1.x*x1.x + x1.y*x1.y + x1.z*x1.z + x1.w*x1.w;
    #pragma unroll
    for (int m = 1; m < 16; m <<= 1) {
        s  += __shfl_xor(s,  m, 64);
        ss += __shfl_xor(ss, m, 64);
    }
    const float mean = s * (1.0f / 128.0f);
    const float var  = ss * (1.0f / 128.0f) - mean * mean;
    const float rstd = rsqrtf(var + LNEPS);
    __syncthreads();   // gb_s + wvf_s4 ready

    {
        const int c0 = seg * 8;
        float4 o0, o1;
        o0.x = (x0.x - mean)*rstd*gb_s[0][c0+0] + gb_s[1][c0+0];
        o0.y = (x0.y - mean)*rstd*gb_s[0][c0+1] + gb_s[1][c0+1];
        o0.z = (x0.z - mean)*rstd*gb_s[0][c0+2] + gb_s[1][c0+2];
        o0.w = (x0.w - mean)*rstd*gb_s[0][c0+3] + gb_s[1][c0+3];
        o1.x = (x1.x - mean)*rstd*gb_s[0][c0+4] + gb_s[1][c0+4];
        o1.y = (x1.y - mean)*rstd*gb_s[0][c0+5] + gb_s[1][c0+5];
        o1.z = (x1.z - mean)*rstd*gb_s[0][c0+6] + gb_s[1][c0+6];
        o1.w = (x1.w - mean)*rstd*gb_s[0][c0+7] + gb_s[1][c0+7];
        ((float4*)qn_s)[r*33 + seg*2 + 0] = o0;
        ((float4*)qn_s)[r*33 + seg*2 + 1] = o1;
    }
    __syncthreads();

    const int rp = t >> 5;
    const int r0 = rp * 2;
    const int cq = t & 31;
    const int sc0 = t >> 2;
    const int si0 = t & 3;
    const float4* qn4 = (const float4*)qn_s;

    for (int w = 0; w < 2; ++w) {
        const float4* W4 = (const float4*)((w == 0) ? Wq : Wk);
        float4 acc0 = make_float4(0.f,0.f,0.f,0.f);
        float4 acc1 = make_float4(0.f,0.f,0.f,0.f);
        {
            float4 g0 = W4[(size_t)sc0*32 + si0];
            float4 g1 = W4[(size_t)(sc0+64)*32 + si0];
            float* wt = wt_s[0];
            wt[(si0*4+0)*132 + sc0] = g0.x; wt[(si0*4+1)*132 + sc0] = g0.y;
            wt[(si0*4+2)*132 + sc0] = g0.z; wt[(si0*4+3)*132 + sc0] = g0.w;
            wt[(si0*4+0)*132 + sc0+64] = g1.x; wt[(si0*4+1)*132 + sc0+64] = g1.y;
            wt[(si0*4+2)*132 + sc0+64] = g1.z; wt[(si0*4+3)*132 + sc0+64] = g1.w;
        }
        __syncthreads();
        #pragma unroll
        for (int tau = 0; tau < 8; ++tau) {
            const int buf = tau & 1;
            float4 ng0, ng1;
            if (tau < 7) {
                ng0 = W4[(size_t)sc0*32 + (tau+1)*4 + si0];
                ng1 = W4[(size_t)(sc0+64)*32 + (tau+1)*4 + si0];
            }
            const float4* wt4 = (const float4*)wt_s[buf];
            #pragma unroll
            for (int e4 = 0; e4 < 4; ++e4) {
                float4 a0 = qn4[r0*33 + tau*4 + e4];
                float4 a1 = qn4[(r0+1)*33 + tau*4 + e4];
                const float* a0p = (const float*)&a0;
                const float* a1p = (const float*)&a1;
                #pragma unroll
                for (int ee = 0; ee < 4; ++ee) {
                    const float4 wv = wt4[(e4*4+ee)*33 + cq];
                    fma4s(acc0, a0p[ee], wv);
                    fma4s(acc1, a1p[ee], wv);
                }
            }
            if (tau < 7) {
                float* wt = wt_s[buf ^ 1];
                wt[(si0*4+0)*132 + sc0] = ng0.x; wt[(si0*4+1)*132 + sc0] = ng0.y;
                wt[(si0*4+2)*132 + sc0] = ng0.z; wt[(si0*4+3)*132 + sc0] = ng0.w;
                wt[(si0*4+0)*132 + sc0+64] = ng1.x; wt[(si0*4+1)*132 + sc0+64] = ng1.y;
                wt[(si0*4+2)*132 + sc0+64] = ng1.z; wt[(si0*4+3)*132 + sc0+64] = ng1.w;
            }
            __syncthreads();
        }
        const float sc = (w == 0) ? 0.25f : 1.0f;   // HD^-0.5 folded into q
        float4* dst = (float4*)(ws + (w == 0 ? WS_Q : WS_K));
        dst[(size_t)(rowbase + r0)*32 + cq]     = scale4(acc0, sc);
        dst[(size_t)(rowbase + r0 + 1)*32 + cq] = scale4(acc1, sc);
    }

    // fv[row][h] = dot128(qn[row], Wv_f[h])  (Wv_f from padded LDS)
    if (t < 128) {
        const int rr = t >> 3, h = t & 7;
        float4 acc = make_float4(0.f,0.f,0.f,0.f);
        #pragma unroll
        for (int ch = 0; ch < 32; ++ch)
            fma4(acc, qn4[rr*33 + ch], wvf_s4[h*33 + ch]);
        ws[WS_FV + (size_t)(rowbase + rr)*NH + h] = hsum4(acc);
    }
}

// ---------------- Kernel 2: attn + force (3 compute barriers) ----------------
// 8192 blocks x 256 threads. In-block G/SG/C from Wbias (L2-hot). Coalesced
// pair -> padded LDS tile. fv staged n-mapped into LDS. Softmax+PV+force fused.
__global__ __launch_bounds__(256, 4) void attn_force_kernel(
    const float* __restrict__ pair, const int* __restrict__ nlist,
    const float* __restrict__ delta_pos, const float* __restrict__ attn_mask,
    const float* __restrict__ pn_g, const float* __restrict__ pn_b,
    const float* __restrict__ Wbias, const float* __restrict__ bbias,
    const float* __restrict__ ws, float* __restrict__ out)
{
    __shared__ float4 pair_s4[64*17];     // 17408 B, padded rows
    __shared__ float  logit_s[NNEIN*9];   // [n][9] stride coprime with 32
    __shared__ float4 G_s4[128];          // G[8][64] head-major
    __shared__ float  csg_s[16];          // SG[0..7], C[8..15]
    __shared__ float  fv_s[NNEIN*9];      // fv gathered, [n][9]
    __shared__ float  dp_s[192];          // delta_pos rows
    __shared__ float  fpart[4][3];

    const int t    = threadIdx.x;
    const int bid  = blockIdx.x;
    const int fr   = bid >> 11;
    const int l    = bid & 2047;
    const int w    = t >> 6;
    const int lane = t & 63;
    const int half = lane >> 5;        // gather mapping
    const int c    = lane & 31;        // k chunk index
    const int n    = t >> 2;           // n-mapping neighbor
    const int sub  = t & 3;
    const int h0   = sub * 2, h1 = h0 + 1;
    const int i32  = lane & 31;        // softmax row index
    const int hh   = t >> 5;           // softmax head

    // ---------------- prefetch / staging (all coalesced or L2-hot) ----------------
    {
        const float4* p4 = (const float4*)pair + (size_t)bid*1024;
        #pragma unroll
        for (int i = 0; i < 4; ++i) {
            const int ci   = i*256 + t;
            const float4 v = p4[ci];
            pair_s4[(ci >> 4)*17 + (ci & 15)] = v;
        }
    }
    const int jv = nlist[(size_t)bid*NNEIN + lane];   // every wave holds full nlist
    const float4 q4c = ((const float4*)(ws + WS_Q))[(size_t)bid*32 + c];

    const float mask0 = attn_mask[((size_t)(fr*NH + h0)*NLOCC + l)*NNEIN + n];
    const float mask1 = attn_mask[((size_t)(fr*NH + h1)*NLOCC + l)*NNEIN + n];

    // G[h][p] = pn_g[p]*Wbias[h][p]; SG/C per head; dp staging
    if (t < 128) {
        const int p4i = t & 15;
        const float4 wb4 = ((const float4*)Wbias)[t];
        const float4 pg4 = ((const float4*)pn_g)[p4i];
        G_s4[t] = make_float4(wb4.x*pg4.x, wb4.y*pg4.y, wb4.z*pg4.z, wb4.w*pg4.w);
    } else if (t < 192) {
        const int h = (t - 128) >> 3, s8 = (t - 128) & 7;
        float sg = 0.f, cb = 0.f;
        #pragma unroll
        for (int k = 0; k < 8; ++k) {
            const int p = s8*8 + k;
            const float wb = Wbias[h*PDIM + p];
            sg = fmaf(pn_g[p], wb, sg);
            cb = fmaf(pn_b[p], wb, cb);
        }
        sg += __shfl_xor(sg, 1, 64); sg += __shfl_xor(sg, 2, 64); sg += __shfl_xor(sg, 4, 64);
        cb += __shfl_xor(cb, 1, 64); cb += __shfl_xor(cb, 2, 64); cb += __shfl_xor(cb, 4, 64);
        if (s8 == 0) { csg_s[h] = sg; csg_s[8 + h] = cb + bbias[h]; }
    } else if (t < 240) {
        ((float4*)dp_s)[t - 192] = ((const float4*)(delta_pos + (size_t)bid*192))[t - 192];
    }

    // fv: float2 per (n,sub) — 4 lanes cover one 32B fv row; stage n-mapped
    {
        const int    jn  = __shfl(jv, n & 63, 64);
        const float2 fv2 = ((const float2*)(ws + WS_FV + ((size_t)(fr << 11) + jn)*NH))[sub];
        fv_s[n*9 + h0] = fv2.x;
        fv_s[n*9 + h1] = fv2.y;
    }

    // ---------------- QK gather + raw logits (gather mapping) ----------------
    {
        const float4* k4 = (const float4*)(ws + WS_K) + (size_t)(fr << 11)*32;
        int jr[8];
        #pragma unroll
        for (int i = 0; i < 8; ++i)
            jr[i] = __shfl(jv, (w << 4) | (i << 1) | half, 64);
        float4 kkA[4], kkB[4];
        #pragma unroll
        for (int i = 0; i < 4; ++i) kkA[i] = k4[(size_t)jr[i]*32 + c];
        #pragma unroll
        for (int i = 0; i < 4; ++i) kkB[i] = k4[(size_t)jr[4+i]*32 + c];
        float p[8];
        #pragma unroll
        for (int i = 0; i < 4; ++i) p[i]     = dot4(kkA[i], q4c);
        #pragma unroll
        for (int i = 0; i < 4; ++i) p[4 + i] = dot4(kkB[i], q4c);
        #pragma unroll
        for (int i = 0; i < 8; ++i) {
            float pp = p[i];
            pp += __shfl_xor(pp, 1, 64);
            pp += __shfl_xor(pp, 2, 64);
            if ((c & 3) == 0)
                logit_s[((w << 4) | (i << 1) | half)*9 + (c >> 2)] = pp;
        }
    }
    __syncthreads();   // (1) pair tile, logits, G, csg, fv, dp staged

    // ---------------- pair LN + bias, RMW into logits (n-mapping) ----------------
    {
        const float4 pr0 = pair_s4[n*17 + sub*4 + 0];
        const float4 pr1 = pair_s4[n*17 + sub*4 + 1];
        const float4 pr2 = pair_s4[n*17 + sub*4 + 2];
        const float4 pr3 = pair_s4[n*17 + sub*4 + 3];
        float s  = hsum4(pr0) + hsum4(pr1) + hsum4(pr2) + hsum4(pr3);
        float ss = dot4(pr0, pr0) + dot4(pr1, pr1) + dot4(pr2, pr2) + dot4(pr3, pr3);
        s  += __shfl_xor(s, 1, 64);  s  += __shfl_xor(s, 2, 64);
        ss += __shfl_xor(ss, 1, 64); ss += __shfl_xor(ss, 2, 64);
        const float mean = s * (1.0f / 64.0f);
        const float var  = ss * (1.0f / 64.0f) - mean * mean;
        const float rstd = rsqrtf(var + LNEPS);

        float d[NH];
        #pragma unroll
        for (int h = 0; h < NH; ++h) d[h] = 0.f;
        const float4 prq[4] = {pr0, pr1, pr2, pr3};
        #pragma unroll
        for (int q = 0; q < 4; ++q) {
            #pragma unroll
            for (int h = 0; h < NH; ++h)
                d[h] += dot4(prq[q], G_s4[h*16 + sub*4 + q]);
        }
        #pragma unroll
        for (int h = 0; h < NH; ++h) {
            d[h] += __shfl_xor(d[h], 1, 64);
            d[h] += __shfl_xor(d[h], 2, 64);
        }
        logit_s[n*9 + h0] += rstd*(d[h0] - mean*csg_s[h0]) + csg_s[8 + h0] + mask0;
        logit_s[n*9 + h1] += rstd*(d[h1] - mean*csg_s[h1]) + csg_s[8 + h1] + mask1;
    }
    __syncthreads();   // (2)

    // ---------------- softmax + PV + force (fused, hh/i32 mapping) ----------------
    {
        const float a = logit_s[i32*9 + hh], b = logit_s[(i32 + 32)*9 + hh];
        float m = fmaxf(a, b);
        #pragma unroll
        for (int mm = 16; mm >= 1; mm >>= 1) m = fmaxf(m, __shfl_xor(m, mm, 64));
        const float ea = __expf(a - m), eb = __expf(b - m);
        float sum = ea + eb;
        #pragma unroll
        for (int mm = 16; mm >= 1; mm >>= 1) sum += __shfl_xor(sum, mm, 64);
        const float inv = 1.0f / sum;
        float ca = ea * inv * fv_s[i32*9 + hh];
        float cb = eb * inv * fv_s[(i32 + 32)*9 + hh];
        ca += __shfl_xor(ca, 32, 64);   // + the wave's other head
        cb += __shfl_xor(cb, 32, 64);
        const float dpax = dp_s[i32*3 + 0],        dpay = dp_s[i32*3 + 1],        dpaz = dp_s[i32*3 + 2];
        const float dpbx = dp_s[(i32+32)*3 + 0],   dpby = dp_s[(i32+32)*3 + 1],   dpbz = dp_s[(i32+32)*3 + 2];
        float f0 = ca*dpax + cb*dpbx;
        float f1 = ca*dpay + cb*dpby;
        float f2 = ca*dpaz + cb*dpbz;
        #pragma unroll
        for (int mm = 1; mm <= 16; mm <<= 1) {
            f0 += __shfl_xor(f0, mm, 64);
            f1 += __shfl_xor(f1, mm, 64);
            f2 += __shfl_xor(f2, mm, 64);
        }
        if (lane == 0) {
            fpart[w][0] = f0; fpart[w][1] = f1; fpart[w][2] = f2;
        }
    }
    __syncthreads();   // (3)

    if (t < 3)
        out[(size_t)bid*3 + t] = fpart[0][t] + fpart[1][t] + fpart[2][t] + fpart[3][t];
}

extern "C" void kernel_launch(void* const* d_in, const int* in_sizes, int n_in,
                              void* d_out, int out_size, void* d_ws, size_t ws_size,
                              hipStream_t stream) {
    const float* query     = (const float*)d_in[0];
    const float* pair      = (const float*)d_in[1];
    const int*   nlist     = (const int*)d_in[2];
    const float* delta_pos = (const float*)d_in[3];
    const float* attn_mask = (const float*)d_in[4];
    const float* ln_g      = (const float*)d_in[5];
    const float* ln_b      = (const float*)d_in[6];
    const float* pn_g      = (const float*)d_in[7];
    const float* pn_b      = (const float*)d_in[8];
    const float* Wq        = (const float*)d_in[9];
    const float* Wk        = (const float*)d_in[10];
    const float* Wv        = (const float*)d_in[11];
    const float* Wbias     = (const float*)d_in[12];
    const float* bbias     = (const float*)d_in[13];
    const float* Wforce    = (const float*)d_in[14];
    float* out = (float*)d_out;
    float* ws  = (float*)d_ws;

    qkfv_kernel<<<512, 256, 0, stream>>>(query, ln_g, ln_b, Wq, Wk, Wv, Wforce, ws);
    attn_force_kernel<<<NROW, 256, 0, stream>>>(pair, nlist, delta_pos, attn_mask,
                                                pn_g, pn_b, Wbias, bbias, ws, out);
}